// Round 1
// baseline (489.441 us; speedup 1.0000x reference)
//
#include <hip/hip_runtime.h>
#include <hip/hip_bf16.h>
#include <math.h>

// Problem constants: B=4, C=D=256, H=W=128, HID=1024, N = B*H*W = 65536.
#define NPIX  65536
#define CCH   256
#define HWSZ  16384
#define WIDTH 128
#define HID   1024

typedef unsigned short u16;
typedef __bf16 bf16x8 __attribute__((ext_vector_type(8)));
typedef float  floatx4 __attribute__((ext_vector_type(4)));

__device__ __forceinline__ float bf2f(u16 u) {
  union { unsigned int i; float f; } c; c.i = ((unsigned int)u) << 16; return c.f;
}
__device__ __forceinline__ float bflo(unsigned int u) {
  union { unsigned int i; float f; } c; c.i = u << 16; return c.f;
}
__device__ __forceinline__ float bfhi(unsigned int u) {
  union { unsigned int i; float f; } c; c.i = u & 0xffff0000u; return c.f;
}
__device__ __forceinline__ u16 f2bf(float f) {
  union { float f; unsigned int i; } c; c.f = f;
  unsigned int x = c.i;
  x += 0x7fffu + ((x >> 16) & 1u);   // round-to-nearest-even
  return (u16)(x >> 16);
}

// async global->LDS, 16B per lane; LDS dest must be wave-uniform base + lane*16.
__device__ __forceinline__ void async16(const void* g, void* l) {
  __builtin_amdgcn_global_load_lds(
      (const __attribute__((address_space(1))) void*)g,
      (__attribute__((address_space(3))) void*)l, 16, 0, 0);
}

// ---------------------------------------------------------------------------
// Weight transpose + fp32->bf16: dst[c*R + r] = bf16(src[r*C + c])
// grid (C/32, R/32), 256 threads
__global__ __launch_bounds__(256) void wtrans_kernel(
    const float* __restrict__ src, u16* __restrict__ dst, int R, int C) {
  __shared__ float tile[32][33];
  const int tx = threadIdx.x & 31, ty = threadIdx.x >> 5;  // 32 x 8
  const int r0 = blockIdx.y * 32, c0 = blockIdx.x * 32;
#pragma unroll
  for (int i = 0; i < 32; i += 8)
    tile[ty + i][tx] = src[(size_t)(r0 + ty + i) * C + c0 + tx];
  __syncthreads();
#pragma unroll
  for (int i = 0; i < 32; i += 8)
    dst[(size_t)(c0 + ty + i) * R + r0 + tx] = f2bf(tile[tx][ty + i]);
}

// ---------------------------------------------------------------------------
// LayerNorm1: x [B,C,H,W] fp32 -> n1 [N,256] bf16 (row = pixel, channel-major)
// Block: 256 threads handles 32 pixels. Coalesced c-major reads, LDS transpose.
__global__ __launch_bounds__(256) void ln1_kernel(
    const float* __restrict__ x, const float* __restrict__ g,
    const float* __restrict__ bb, u16* __restrict__ n1) {
  __shared__ float sx[32][257];
  __shared__ float sred[16][32];
  __shared__ float sm[32], sr[32];
  const int tx = threadIdx.x;
  const int p0 = blockIdx.x * 32;
  {
    const int pix = tx & 31, cpart = tx >> 5;  // cpart 0..7 (32 channels each)
    const int p = p0 + pix;
    const int b = p >> 14, hw = p & (HWSZ - 1);
    const float* xb = x + ((size_t)b * CCH) * HWSZ + hw;
    float s = 0.f, s2 = 0.f;
#pragma unroll 4
    for (int i = 0; i < 32; i++) {
      const int c = cpart * 32 + i;
      const float v = xb[(size_t)c * HWSZ];
      sx[pix][c] = v;
      s += v; s2 += v * v;
    }
    sred[cpart][pix] = s; sred[8 + cpart][pix] = s2;
  }
  __syncthreads();
  if (tx < 32) {
    float s = 0.f, s2 = 0.f;
#pragma unroll
    for (int j = 0; j < 8; j++) { s += sred[j][tx]; s2 += sred[8 + j][tx]; }
    const float m = s * (1.0f / 256.0f);
    const float var = s2 * (1.0f / 256.0f) - m * m;
    sm[tx] = m; sr[tx] = rsqrtf(var + 1e-5f);
  }
  __syncthreads();
  const float gc = g[tx], bc = bb[tx];
#pragma unroll 4
  for (int i = 0; i < 32; i++) {
    const float v = (sx[i][tx] - sm[i]) * sr[i] * gc + bc;
    n1[(size_t)(p0 + i) * CCH + tx] = f2bf(v);
  }
}

// ---------------------------------------------------------------------------
// Residual + LayerNorm2: x1 = x + attn (fp32 out), n2 = LN(x1) bf16
__global__ __launch_bounds__(256) void res_ln2_kernel(
    const float* __restrict__ x, const u16* __restrict__ attn,
    const float* __restrict__ g, const float* __restrict__ bb,
    float* __restrict__ x1, u16* __restrict__ n2) {
  __shared__ float sx[32][257];
  __shared__ float sred[16][32];
  __shared__ float sm[32], sr[32];
  const int tx = threadIdx.x;
  const int p0 = blockIdx.x * 32;
  {
    const int pix = tx & 31, cpart = tx >> 5;
    const int p = p0 + pix;
    const int b = p >> 14, hw = p & (HWSZ - 1);
    const float* xb = x + ((size_t)b * CCH) * HWSZ + hw;
#pragma unroll 4
    for (int i = 0; i < 32; i++) {
      const int c = cpart * 32 + i;
      sx[pix][c] = xb[(size_t)c * HWSZ];
    }
  }
  __syncthreads();
#pragma unroll 4
  for (int i = 0; i < 32; i++) {
    const float v = sx[i][tx] + bf2f(attn[(size_t)(p0 + i) * CCH + tx]);
    sx[i][tx] = v;
    x1[(size_t)(p0 + i) * CCH + tx] = v;
  }
  __syncthreads();
  {
    const int pix = tx & 31, cpart = tx >> 5;
    float s = 0.f, s2 = 0.f;
#pragma unroll 4
    for (int i = 0; i < 32; i++) {
      const float v = sx[pix][cpart * 32 + i];
      s += v; s2 += v * v;
    }
    sred[cpart][pix] = s; sred[8 + cpart][pix] = s2;
  }
  __syncthreads();
  if (tx < 32) {
    float s = 0.f, s2 = 0.f;
#pragma unroll
    for (int j = 0; j < 8; j++) { s += sred[j][tx]; s2 += sred[8 + j][tx]; }
    const float m = s * (1.0f / 256.0f);
    const float var = s2 * (1.0f / 256.0f) - m * m;
    sm[tx] = m; sr[tx] = rsqrtf(var + 1e-5f);
  }
  __syncthreads();
  const float gc = g[tx], bc = bb[tx];
#pragma unroll 4
  for (int i = 0; i < 32; i++) {
    const float v = (sx[i][tx] - sm[i]) * sr[i] * gc + bc;
    n2[(size_t)(p0 + i) * CCH + tx] = f2bf(v);
  }
}

// ---------------------------------------------------------------------------
// 3x3 neighborhood attention. One wave per pixel; lanes span channels (4 each).
__global__ __launch_bounds__(256) void attn_kernel(
    const u16* __restrict__ q, const u16* __restrict__ k,
    const u16* __restrict__ v, u16* __restrict__ attn) {
  const int tid = threadIdx.x;
  const int wave = tid >> 6, lane = tid & 63;
  const int p = blockIdx.x * 4 + wave;
  const int hw = p & (HWSZ - 1);
  const int hh = hw >> 7, ww = hw & (WIDTH - 1);
  const size_t co = (size_t)p * CCH + lane * 4;
  const uint2 qr = *(const uint2*)(q + co);
  const float qf0 = bflo(qr.x), qf1 = bfhi(qr.x);
  const float qf2 = bflo(qr.y), qf3 = bfhi(qr.y);
  float sc[9];
#pragma unroll
  for (int n = 0; n < 9; n++) {
    const int dy = n / 3 - 1, dx = n % 3 - 1;
    const int y = hh + dy, x2 = ww + dx;
    float s = -1e30f;
    if (y >= 0 && y < 128 && x2 >= 0 && x2 < 128) {   // wave-uniform branch
      const uint2 kr = *(const uint2*)(k + co + dy * (WIDTH * CCH) + dx * CCH);
      float d = qf0 * bflo(kr.x) + qf1 * bfhi(kr.x)
              + qf2 * bflo(kr.y) + qf3 * bfhi(kr.y);
#pragma unroll
      for (int o = 32; o >= 1; o >>= 1) d += __shfl_xor(d, o, 64);
      s = d * 0.0625f;   // 1/sqrt(256)
    }
    sc[n] = s;
  }
  float mx = sc[0];
#pragma unroll
  for (int n = 1; n < 9; n++) mx = fmaxf(mx, sc[n]);
  float wgt[9], wsum = 0.f;
#pragma unroll
  for (int n = 0; n < 9; n++) { wgt[n] = __expf(sc[n] - mx); wsum += wgt[n]; }
  const float inv = 1.0f / wsum;
  float a0 = 0.f, a1 = 0.f, a2 = 0.f, a3 = 0.f;
#pragma unroll
  for (int n = 0; n < 9; n++) {
    const int dy = n / 3 - 1, dx = n % 3 - 1;
    const int y = hh + dy, x2 = ww + dx;
    if (y >= 0 && y < 128 && x2 >= 0 && x2 < 128) {
      const uint2 vr = *(const uint2*)(v + co + dy * (WIDTH * CCH) + dx * CCH);
      const float wn = wgt[n] * inv;
      a0 += wn * bflo(vr.x); a1 += wn * bfhi(vr.x);
      a2 += wn * bflo(vr.y); a3 += wn * bfhi(vr.y);
    }
  }
  uint2 o;
  o.x = ((unsigned int)f2bf(a1) << 16) | (unsigned int)f2bf(a0);
  o.y = ((unsigned int)f2bf(a3) << 16) | (unsigned int)f2bf(a2);
  *(uint2*)(attn + co) = o;
}

// ---------------------------------------------------------------------------
// bf16 MFMA GEMM, m97 structure: 128x128 tile, BK=32, 4 waves each 64x64.
// A [M,K] bf16 K-major, BT [N,K] bf16 K-major. C = A*B^T.
// EPI 0: out = bf16(acc + bias[n])        -> outb [M,Nn]
// EPI 1: out = bf16(gelu(acc + bias[n]))  -> outb [M,Nn]
// EPI 2: val = acc + bias[n] + x1[m*256+n]; store fp32 transposed [B,C,H,W]
template <int EPI>
__global__ __launch_bounds__(256, 2) void gemm_kernel(
    const u16* __restrict__ A, const u16* __restrict__ BT,
    const float* __restrict__ bias, const float* __restrict__ x1,
    u16* __restrict__ outb, float* __restrict__ outf, int K, int Nn) {
  __shared__ u16 sA[4096];   // 128 rows x 32 bf16
  __shared__ u16 sB[4096];
  const int tid = threadIdx.x;
  const int wave = tid >> 6;
  const int lane = tid & 63;
  const int quad = lane >> 4;
  const int l16 = lane & 15;
  const int m0 = blockIdx.x * 128;
  const int n0 = blockIdx.y * 128;
  const int wr = (wave >> 1) * 64;
  const int wc = (wave & 1) * 64;

  floatx4 acc[4][4];
#pragma unroll
  for (int i = 0; i < 4; i++)
#pragma unroll
    for (int j = 0; j < 4; j++) acc[i][j] = (floatx4){0.f, 0.f, 0.f, 0.f};

  // staging: chunk ci covers (row = ci>>2, 8 bf16 at k = (ci&3)*8); 2 rounds.
  const int ci0 = tid, ci1 = tid + 256;
  const u16* aP0 = A + (size_t)(m0 + (ci0 >> 2)) * K + (ci0 & 3) * 8;
  const u16* aP1 = A + (size_t)(m0 + (ci1 >> 2)) * K + (ci1 & 3) * 8;
  const u16* bP0 = BT + (size_t)(n0 + (ci0 >> 2)) * K + (ci0 & 3) * 8;
  const u16* bP1 = BT + (size_t)(n0 + (ci1 >> 2)) * K + (ci1 & 3) * 8;
  u16* sA0 = &sA[(wave * 64) * 8];          // wave-uniform LDS bases
  u16* sA1 = &sA[(256 + wave * 64) * 8];
  u16* sB0 = &sB[(wave * 64) * 8];
  u16* sB1 = &sB[(256 + wave * 64) * 8];

  for (int k0 = 0; k0 < K; k0 += 32) {
    async16(aP0 + k0, sA0);
    async16(aP1 + k0, sA1);
    async16(bP0 + k0, sB0);
    async16(bP1 + k0, sB1);
    __syncthreads();   // drains vmcnt then barrier: tiles visible
    bf16x8 af[4], bfv[4];
#pragma unroll
    for (int mi = 0; mi < 4; mi++)
      af[mi] = *(const bf16x8*)&sA[(wr + mi * 16 + l16) * 32 + quad * 8];
#pragma unroll
    for (int ni = 0; ni < 4; ni++)
      bfv[ni] = *(const bf16x8*)&sB[(wc + ni * 16 + l16) * 32 + quad * 8];
#pragma unroll
    for (int mi = 0; mi < 4; mi++)
#pragma unroll
      for (int ni = 0; ni < 4; ni++)
        acc[mi][ni] = __builtin_amdgcn_mfma_f32_16x16x32_bf16(
            af[mi], bfv[ni], acc[mi][ni], 0, 0, 0);
    __syncthreads();   // all waves done reading before next stage
  }

  // Epilogue. C/D layout per tile: col = lane&15, row = quad*4 + reg.
#pragma unroll
  for (int mi = 0; mi < 4; mi++) {
#pragma unroll
    for (int ni = 0; ni < 4; ni++) {
      const int col = n0 + wc + ni * 16 + l16;
      const float bs = bias[col];
#pragma unroll
      for (int r = 0; r < 4; r++) {
        const int row = m0 + wr + mi * 16 + quad * 4 + r;
        float val = acc[mi][ni][r] + bs;
        if (EPI == 0) {
          outb[(size_t)row * Nn + col] = f2bf(val);
        } else if (EPI == 1) {
          val = 0.5f * val * (1.0f + erff(val * 0.70710678118654752f));
          outb[(size_t)row * Nn + col] = f2bf(val);
        } else {
          val += x1[(size_t)row * CCH + col];
          const int b = row >> 14, hw = row & (HWSZ - 1);
          outf[((size_t)(b * CCH + col)) * HWSZ + hw] = val;
        }
      }
    }
  }
}

// ---------------------------------------------------------------------------
extern "C" void kernel_launch(void* const* d_in, const int* in_sizes, int n_in,
                              void* d_out, int out_size, void* d_ws, size_t ws_size,
                              hipStream_t stream) {
  const float* x    = (const float*)d_in[0];
  const float* wq   = (const float*)d_in[1];
  const float* bq   = (const float*)d_in[2];
  const float* wk   = (const float*)d_in[3];
  const float* bk   = (const float*)d_in[4];
  const float* wv   = (const float*)d_in[5];
  const float* bv   = (const float*)d_in[6];
  const float* ln1g = (const float*)d_in[7];
  const float* ln1b = (const float*)d_in[8];
  const float* ln2g = (const float*)d_in[9];
  const float* ln2b = (const float*)d_in[10];
  const float* fc1w = (const float*)d_in[11];
  const float* fc1b = (const float*)d_in[12];
  const float* fc2w = (const float*)d_in[13];
  const float* fc2b = (const float*)d_in[14];
  float* out = (float*)d_out;

  // Workspace layout (liveness-checked aliasing), total ~225.4 MB:
  //   [0,64)    MB : x1 fp32            (live K4 -> K7)
  //   [64,192)  MB : h bf16 [N,1024]    (live K6 -> K7); inside it:
  //       [64,96)   : k bf16   (dead after attention, before h written)
  //       [96,128)  : v bf16   (dead after attention)
  //       [128,160) : n1/attn  (n1 dead after QKV; attn dead after res_ln2)
  //   [192,224) MB : q bf16 / n2 bf16   (q dead after attention; n2 live K5->K6)
  //   [224,~225.4)  : bf16 transposed weights
  char* ws = (char*)d_ws;
  const size_t MB = (size_t)1 << 20;
  float* x1  = (float*)(ws);
  u16* hbuf  = (u16*)(ws + 64 * MB);
  u16* kbuf  = (u16*)(ws + 64 * MB);
  u16* vbuf  = (u16*)(ws + 96 * MB);
  u16* n1    = (u16*)(ws + 128 * MB);
  u16* attnb = n1;
  u16* qbuf  = (u16*)(ws + 192 * MB);
  u16* n2    = qbuf;
  u16* wqT   = (u16*)(ws + 224 * MB);
  u16* wkT   = wqT + 256 * 256;
  u16* wvT   = wkT + 256 * 256;
  u16* f1T   = wvT + 256 * 256;     // [1024,256]
  u16* f2T   = f1T + 1024 * 256;    // [256,1024]

  dim3 blk(256);
  // weight prep (ws is re-poisoned every call, so redo every call)
  wtrans_kernel<<<dim3(8, 8), blk, 0, stream>>>(wq, wqT, 256, 256);
  wtrans_kernel<<<dim3(8, 8), blk, 0, stream>>>(wk, wkT, 256, 256);
  wtrans_kernel<<<dim3(8, 8), blk, 0, stream>>>(wv, wvT, 256, 256);
  wtrans_kernel<<<dim3(32, 8), blk, 0, stream>>>(fc1w, f1T, 256, 1024);
  wtrans_kernel<<<dim3(8, 32), blk, 0, stream>>>(fc2w, f2T, 1024, 256);

  ln1_kernel<<<NPIX / 32, blk, 0, stream>>>(x, ln1g, ln1b, n1);

  gemm_kernel<0><<<dim3(512, 2), blk, 0, stream>>>(n1, wqT, bq, nullptr, qbuf, nullptr, 256, 256);
  gemm_kernel<0><<<dim3(512, 2), blk, 0, stream>>>(n1, wkT, bk, nullptr, kbuf, nullptr, 256, 256);
  gemm_kernel<0><<<dim3(512, 2), blk, 0, stream>>>(n1, wvT, bv, nullptr, vbuf, nullptr, 256, 256);

  attn_kernel<<<NPIX / 4, blk, 0, stream>>>(qbuf, kbuf, vbuf, attnb);

  res_ln2_kernel<<<NPIX / 32, blk, 0, stream>>>(x, attnb, ln2g, ln2b, x1, n2);

  gemm_kernel<1><<<dim3(512, 8), blk, 0, stream>>>(n2, f1T, fc1b, nullptr, hbuf, nullptr, 256, HID);
  gemm_kernel<2><<<dim3(512, 2), blk, 0, stream>>>(hbuf, f2T, fc2b, x1, nullptr, out, HID, 256);
}

// Round 2
// 485.847 us; speedup vs baseline: 1.0074x; 1.0074x over previous
//
#include <hip/hip_runtime.h>
#include <hip/hip_bf16.h>
#include <math.h>

// Problem constants: B=4, C=D=256, H=W=128, HID=1024, N = B*H*W = 65536.
#define NPIX  65536
#define CCH   256
#define HWSZ  16384
#define WIDTH 128
#define HID   1024

typedef unsigned short u16;
typedef __bf16 bf16x8 __attribute__((ext_vector_type(8)));
typedef float  floatx4 __attribute__((ext_vector_type(4)));

__device__ __forceinline__ float bf2f(u16 u) {
  union { unsigned int i; float f; } c; c.i = ((unsigned int)u) << 16; return c.f;
}
__device__ __forceinline__ float bflo(unsigned int u) {
  union { unsigned int i; float f; } c; c.i = u << 16; return c.f;
}
__device__ __forceinline__ float bfhi(unsigned int u) {
  union { unsigned int i; float f; } c; c.i = u & 0xffff0000u; return c.f;
}
__device__ __forceinline__ u16 f2bf(float f) {
  union { float f; unsigned int i; } c; c.f = f;
  unsigned int x = c.i;
  x += 0x7fffu + ((x >> 16) & 1u);   // round-to-nearest-even
  return (u16)(x >> 16);
}

// async global->LDS, 16B per lane; LDS dest is wave-uniform base + lane*16.
__device__ __forceinline__ void async16(const void* g, void* l) {
  __builtin_amdgcn_global_load_lds(
      (const __attribute__((address_space(1))) void*)g,
      (__attribute__((address_space(3))) void*)l, 16, 0, 0);
}

// ---------------------------------------------------------------------------
// Weight transpose + fp32->bf16: dst[c*R + r] = bf16(src[r*C + c])
__global__ __launch_bounds__(256) void wtrans_kernel(
    const float* __restrict__ src, u16* __restrict__ dst, int R, int C) {
  __shared__ float tile[32][33];
  const int tx = threadIdx.x & 31, ty = threadIdx.x >> 5;  // 32 x 8
  const int r0 = blockIdx.y * 32, c0 = blockIdx.x * 32;
#pragma unroll
  for (int i = 0; i < 32; i += 8)
    tile[ty + i][tx] = src[(size_t)(r0 + ty + i) * C + c0 + tx];
  __syncthreads();
#pragma unroll
  for (int i = 0; i < 32; i += 8)
    dst[(size_t)(c0 + ty + i) * R + r0 + tx] = f2bf(tile[tx][ty + i]);
}

__global__ __launch_bounds__(256) void concat_bias_kernel(
    const float* __restrict__ bq, const float* __restrict__ bk,
    const float* __restrict__ bv, float* __restrict__ dst) {
  const int i = blockIdx.x * 256 + threadIdx.x;   // grid 3
  if (i < 256) dst[i] = bq[i];
  else if (i < 512) dst[i] = bk[i - 256];
  else if (i < 768) dst[i] = bv[i - 512];
}

// ---------------------------------------------------------------------------
// LayerNorm1: x [B,C,H,W] fp32 -> n1 [N,256] bf16
__global__ __launch_bounds__(256) void ln1_kernel(
    const float* __restrict__ x, const float* __restrict__ g,
    const float* __restrict__ bb, u16* __restrict__ n1) {
  __shared__ float sx[32][257];
  __shared__ float sred[16][32];
  __shared__ float sm[32], sr[32];
  const int tx = threadIdx.x;
  const int p0 = blockIdx.x * 32;
  {
    const int pix = tx & 31, cpart = tx >> 5;
    const int p = p0 + pix;
    const int b = p >> 14, hw = p & (HWSZ - 1);
    const float* xb = x + ((size_t)b * CCH) * HWSZ + hw;
    float s = 0.f, s2 = 0.f;
#pragma unroll 4
    for (int i = 0; i < 32; i++) {
      const int c = cpart * 32 + i;
      const float v = xb[(size_t)c * HWSZ];
      sx[pix][c] = v;
      s += v; s2 += v * v;
    }
    sred[cpart][pix] = s; sred[8 + cpart][pix] = s2;
  }
  __syncthreads();
  if (tx < 32) {
    float s = 0.f, s2 = 0.f;
#pragma unroll
    for (int j = 0; j < 8; j++) { s += sred[j][tx]; s2 += sred[8 + j][tx]; }
    const float m = s * (1.0f / 256.0f);
    const float var = s2 * (1.0f / 256.0f) - m * m;
    sm[tx] = m; sr[tx] = rsqrtf(var + 1e-5f);
  }
  __syncthreads();
  const float gc = g[tx], bc = bb[tx];
#pragma unroll 4
  for (int i = 0; i < 32; i++) {
    const float v = (sx[i][tx] - sm[i]) * sr[i] * gc + bc;
    n1[(size_t)(p0 + i) * CCH + tx] = f2bf(v);
  }
}

// ---------------------------------------------------------------------------
// Residual + LayerNorm2: x1 = x + attn (fp32 out), n2 = LN(x1) bf16
__global__ __launch_bounds__(256) void res_ln2_kernel(
    const float* __restrict__ x, const u16* __restrict__ attn,
    const float* __restrict__ g, const float* __restrict__ bb,
    float* __restrict__ x1, u16* __restrict__ n2) {
  __shared__ float sx[32][257];
  __shared__ float sred[16][32];
  __shared__ float sm[32], sr[32];
  const int tx = threadIdx.x;
  const int p0 = blockIdx.x * 32;
  {
    const int pix = tx & 31, cpart = tx >> 5;
    const int p = p0 + pix;
    const int b = p >> 14, hw = p & (HWSZ - 1);
    const float* xb = x + ((size_t)b * CCH) * HWSZ + hw;
#pragma unroll 4
    for (int i = 0; i < 32; i++) {
      const int c = cpart * 32 + i;
      sx[pix][c] = xb[(size_t)c * HWSZ];
    }
  }
  __syncthreads();
#pragma unroll 4
  for (int i = 0; i < 32; i++) {
    const float v = sx[i][tx] + bf2f(attn[(size_t)(p0 + i) * CCH + tx]);
    sx[i][tx] = v;
    x1[(size_t)(p0 + i) * CCH + tx] = v;
  }
  __syncthreads();
  {
    const int pix = tx & 31, cpart = tx >> 5;
    float s = 0.f, s2 = 0.f;
#pragma unroll 4
    for (int i = 0; i < 32; i++) {
      const float v = sx[pix][cpart * 32 + i];
      s += v; s2 += v * v;
    }
    sred[cpart][pix] = s; sred[8 + cpart][pix] = s2;
  }
  __syncthreads();
  if (tx < 32) {
    float s = 0.f, s2 = 0.f;
#pragma unroll
    for (int j = 0; j < 8; j++) { s += sred[j][tx]; s2 += sred[8 + j][tx]; }
    const float m = s * (1.0f / 256.0f);
    const float var = s2 * (1.0f / 256.0f) - m * m;
    sm[tx] = m; sr[tx] = rsqrtf(var + 1e-5f);
  }
  __syncthreads();
  const float gc = g[tx], bc = bb[tx];
#pragma unroll 4
  for (int i = 0; i < 32; i++) {
    const float v = (sx[i][tx] - sm[i]) * sr[i] * gc + bc;
    n2[(size_t)(p0 + i) * CCH + tx] = f2bf(v);
  }
}

// ---------------------------------------------------------------------------
// 3x3 neighborhood attention over fused qkv [N,768] (q|k|v per row).
__global__ __launch_bounds__(256) void attn_kernel(
    const u16* __restrict__ qkv, u16* __restrict__ attn) {
  const int tid = threadIdx.x;
  const int wave = tid >> 6, lane = tid & 63;
  const int p = blockIdx.x * 4 + wave;
  const int hw = p & (HWSZ - 1);
  const int hh = hw >> 7, ww = hw & (WIDTH - 1);
  const u16* rowp = qkv + (size_t)p * 768 + lane * 4;
  const uint2 qr = *(const uint2*)rowp;
  const float qf0 = bflo(qr.x), qf1 = bfhi(qr.x);
  const float qf2 = bflo(qr.y), qf3 = bfhi(qr.y);
  float sc[9];
#pragma unroll
  for (int n = 0; n < 9; n++) {
    const int dy = n / 3 - 1, dx = n % 3 - 1;
    const int y = hh + dy, x2 = ww + dx;
    float s = -1e30f;
    if (y >= 0 && y < 128 && x2 >= 0 && x2 < 128) {   // wave-uniform branch
      const uint2 kr = *(const uint2*)(rowp + 256 + (dy * WIDTH + dx) * 768);
      float d = qf0 * bflo(kr.x) + qf1 * bfhi(kr.x)
              + qf2 * bflo(kr.y) + qf3 * bfhi(kr.y);
#pragma unroll
      for (int o = 32; o >= 1; o >>= 1) d += __shfl_xor(d, o, 64);
      s = d * 0.0625f;   // 1/sqrt(256)
    }
    sc[n] = s;
  }
  float mx = sc[0];
#pragma unroll
  for (int n = 1; n < 9; n++) mx = fmaxf(mx, sc[n]);
  float wgt[9], wsum = 0.f;
#pragma unroll
  for (int n = 0; n < 9; n++) { wgt[n] = __expf(sc[n] - mx); wsum += wgt[n]; }
  const float inv = 1.0f / wsum;
  float a0 = 0.f, a1 = 0.f, a2 = 0.f, a3 = 0.f;
#pragma unroll
  for (int n = 0; n < 9; n++) {
    const int dy = n / 3 - 1, dx = n % 3 - 1;
    const int y = hh + dy, x2 = ww + dx;
    if (y >= 0 && y < 128 && x2 >= 0 && x2 < 128) {
      const uint2 vr = *(const uint2*)(rowp + 512 + (dy * WIDTH + dx) * 768);
      const float wn = wgt[n] * inv;
      a0 += wn * bflo(vr.x); a1 += wn * bfhi(vr.x);
      a2 += wn * bflo(vr.y); a3 += wn * bfhi(vr.y);
    }
  }
  uint2 o;
  o.x = ((unsigned int)f2bf(a1) << 16) | (unsigned int)f2bf(a0);
  o.y = ((unsigned int)f2bf(a3) << 16) | (unsigned int)f2bf(a2);
  *(uint2*)(attn + (size_t)p * CCH + lane * 4) = o;
}

// ---------------------------------------------------------------------------
// Register-A GEMM: C[M x NCH*64] = A[M x KCH*KT] * BT^T, bf16 in, fp32 acc.
// Block: 256 thr / 4 waves, 128 rows. A fragments live in VGPRs (loaded
// straight from global, read exactly once). B (weights) staged in LDS with a
// 64B-pad-per-8-cols layout -> conflict-free ds_read_b128 frag reads.
// Waves: 2(row-halves) x 2(col-quarters); per 64-col chunk each wave does
// 4x2 MFMA tiles over KT/32 k-steps between one barrier pair.
// EPI 0: bf16(acc+bias) -> outb [M,768]
// EPI 1: bf16(gelu_tanh(acc+bias)) -> outb [M,1024]
// EPI 2: acc+bias+x1 -> fp32 transposed [B,C,H,W]
template <int NCH, int KCH, int KT, int EPI>
__global__ __launch_bounds__(256, 2) void gemm_regA(
    const u16* __restrict__ A, const u16* __restrict__ BT,
    const float* __restrict__ bias, const float* __restrict__ x1,
    u16* __restrict__ outb, float* __restrict__ outf, int Kglb) {
  constexpr int KS   = KT / 32;              // MFMA k-steps per chunk
  constexpr int K16  = KT / 8;               // 16B units per col
  constexpr int CPC  = 512 / KT;             // cols per async wave-call (2|4)
  constexpr int CSU  = KT;                   // col stride (u16)
  constexpr int GSU  = (8 * KT * 2 + 64) / 2;  // 8-col group stride (u16)
  constexpr int NACC = (KCH > 1) ? NCH : 1;
  __shared__ u16 sB[8 * GSU];

  const int tid  = threadIdx.x;
  const int wave = tid >> 6, lane = tid & 63;
  const int quad = lane >> 4, l16 = lane & 15;
  const int m0 = blockIdx.x * 128;
  const int wr  = (wave & 1) * 64;
  const int wcq = (wave >> 1) * 32;

  // B-frag LDS bases (u16) for this lane's two 16-col groups
  const int c0 = wcq + l16, c1 = c0 + 16;
  const int sb0 = (c0 >> 3) * GSU + (c0 & 7) * CSU;
  const int sb1 = (c1 >> 3) * GSU + (c1 & 7) * CSU;

  // staging constants
  const int stc   = wave * 16;                 // this wave's col base
  const int stcol = (lane * 16) / (KT * 2);    // col offset within a call
  const int stk   = lane & (K16 - 1);          // 16B unit within col

  const u16* aRow = A + (size_t)(m0 + wr + l16) * Kglb + quad * 8;

  bf16x8 afr[4][KS];
  floatx4 acc[NACC][4][2];

  auto stage = [&](int idx) {
    const int kc = idx / NCH, ch = idx % NCH;
    const u16* gB = BT + kc * KT + stk * 8;
#pragma unroll
    for (int i = 0; i < 16 / CPC; i++) {
      const int cc = stc + i * CPC;
      async16(gB + (size_t)(ch * 64 + cc + stcol) * Kglb,
              sB + (cc >> 3) * GSU + (cc & 7) * CSU);
    }
  };
  auto loadA = [&](int kc) {
#pragma unroll
    for (int mi = 0; mi < 4; mi++)
#pragma unroll
      for (int ks = 0; ks < KS; ks++)
        afr[mi][ks] = *(const bf16x8*)(aRow + (size_t)mi * 16 * Kglb + kc * KT + ks * 32);
  };
  auto compute = [&](int ci) {
#pragma unroll
    for (int ks = 0; ks < KS; ks++) {
      const int ko = (ks * 4 + quad) * 8;
      const bf16x8 b0 = *(const bf16x8*)&sB[sb0 + ko];
      const bf16x8 b1 = *(const bf16x8*)&sB[sb1 + ko];
#pragma unroll
      for (int mi = 0; mi < 4; mi++) {
        acc[ci][mi][0] = __builtin_amdgcn_mfma_f32_16x16x32_bf16(
            afr[mi][ks], b0, acc[ci][mi][0], 0, 0, 0);
        acc[ci][mi][1] = __builtin_amdgcn_mfma_f32_16x16x32_bf16(
            afr[mi][ks], b1, acc[ci][mi][1], 0, 0, 0);
      }
    }
  };
  auto epilogue = [&](int ci, int ch) {
#pragma unroll
    for (int mi = 0; mi < 4; mi++)
#pragma unroll
      for (int ni = 0; ni < 2; ni++) {
        const int col = ch * 64 + wcq + ni * 16 + l16;
        const float bs = bias[col];
#pragma unroll
        for (int r = 0; r < 4; r++) {
          const int row = m0 + wr + mi * 16 + quad * 4 + r;
          float val = acc[ci][mi][ni][r] + bs;
          if constexpr (EPI == 0) {
            outb[(size_t)row * 768 + col] = f2bf(val);
          } else if constexpr (EPI == 1) {
            const float t = 0.7978845608028654f * (val + 0.044715f * val * val * val);
            const float e = __expf(2.0f * t);
            const float th = 1.0f - 2.0f / (e + 1.0f);   // tanh, inf-safe
            val = 0.5f * val * (1.0f + th);
            outb[(size_t)row * HID + col] = f2bf(val);
          } else {
            val += x1[(size_t)row * CCH + col];
            outf[((size_t)((row >> 14) * CCH + col)) * HWSZ + (row & (HWSZ - 1))] = val;
          }
        }
      }
  };

  if constexpr (KCH == 1) {
    stage(0);
    loadA(0);
#pragma unroll 1
    for (int ch = 0; ch < NCH; ++ch) {
      __syncthreads();                      // staging of chunk ch complete
#pragma unroll
      for (int mi = 0; mi < 4; mi++)
#pragma unroll
        for (int ni = 0; ni < 2; ni++)
          acc[0][mi][ni] = (floatx4){0.f, 0.f, 0.f, 0.f};
      compute(0);
      __syncthreads();                      // all waves done reading sB
      if (ch + 1 < NCH) stage(ch + 1);      // async prefetch next chunk
      epilogue(0, ch);
    }
  } else {
    stage(0);
#pragma unroll
    for (int ci = 0; ci < NACC; ci++)
#pragma unroll
      for (int mi = 0; mi < 4; mi++)
#pragma unroll
        for (int ni = 0; ni < 2; ni++)
          acc[ci][mi][ni] = (floatx4){0.f, 0.f, 0.f, 0.f};
#pragma unroll 1
    for (int kc = 0; kc < KCH; ++kc) {
      loadA(kc);
#pragma unroll
      for (int ch = 0; ch < NCH; ++ch) {
        __syncthreads();
        compute(ch);
        __syncthreads();
        const int nxt = kc * NCH + ch + 1;
        if (nxt < KCH * NCH) stage(nxt);
      }
    }
#pragma unroll
    for (int ch = 0; ch < NCH; ++ch) epilogue(ch, ch);
  }
}

// ---------------------------------------------------------------------------
extern "C" void kernel_launch(void* const* d_in, const int* in_sizes, int n_in,
                              void* d_out, int out_size, void* d_ws, size_t ws_size,
                              hipStream_t stream) {
  const float* x    = (const float*)d_in[0];
  const float* wq   = (const float*)d_in[1];
  const float* bq   = (const float*)d_in[2];
  const float* wk   = (const float*)d_in[3];
  const float* bk   = (const float*)d_in[4];
  const float* wv   = (const float*)d_in[5];
  const float* bv   = (const float*)d_in[6];
  const float* ln1g = (const float*)d_in[7];
  const float* ln1b = (const float*)d_in[8];
  const float* ln2g = (const float*)d_in[9];
  const float* ln2b = (const float*)d_in[10];
  const float* fc1w = (const float*)d_in[11];
  const float* fc1b = (const float*)d_in[12];
  const float* fc2w = (const float*)d_in[13];
  const float* fc2b = (const float*)d_in[14];
  float* out = (float*)d_out;

  // Workspace (aliased by liveness), total ~225.4 MB:
  //   [0,64)    x1 fp32                (res_ln2 -> fc2)
  //   [64,192)  h bf16 [N,1024]        (fc1 -> fc2); overlays:
  //     [64,160)  qkv bf16 [N,768]     (qkv-gemm -> attn)
  //     [160,192) n1 / attn bf16       (ln1 -> qkv-gemm; attn -> res_ln2)
  //   [192,224) n2 bf16                (res_ln2 -> fc1)
  //   [224,..)  bf16 weights + fused bias
  char* ws = (char*)d_ws;
  const size_t MB = (size_t)1 << 20;
  float* x1   = (float*)(ws);
  u16* qkv    = (u16*)(ws + 64 * MB);
  u16* hbuf   = (u16*)(ws + 64 * MB);
  u16* n1     = (u16*)(ws + 160 * MB);
  u16* attnb  = n1;
  u16* n2     = (u16*)(ws + 192 * MB);
  u16* wqkvT  = (u16*)(ws + 224 * MB);      // [768,256]
  u16* f1T    = wqkvT + 768 * 256;          // [1024,256]
  u16* f2T    = f1T + 1024 * 256;           // [256,1024]
  float* bqkv = (float*)(f2T + 256 * 1024); // [768]

  dim3 blk(256);
  wtrans_kernel<<<dim3(8, 8), blk, 0, stream>>>(wq, wqkvT, 256, 256);
  wtrans_kernel<<<dim3(8, 8), blk, 0, stream>>>(wk, wqkvT + 256 * 256, 256, 256);
  wtrans_kernel<<<dim3(8, 8), blk, 0, stream>>>(wv, wqkvT + 512 * 256, 256, 256);
  wtrans_kernel<<<dim3(32, 8), blk, 0, stream>>>(fc1w, f1T, 256, 1024);
  wtrans_kernel<<<dim3(8, 32), blk, 0, stream>>>(fc2w, f2T, 1024, 256);
  concat_bias_kernel<<<dim3(3), blk, 0, stream>>>(bq, bk, bv, bqkv);

  ln1_kernel<<<NPIX / 32, blk, 0, stream>>>(x, ln1g, ln1b, n1);

  // fused QKV: [N,256] x [768,256]^T -> qkv [N,768]
  gemm_regA<12, 1, 256, 0><<<dim3(512), blk, 0, stream>>>(
      n1, wqkvT, bqkv, nullptr, qkv, nullptr, 256);

  attn_kernel<<<NPIX / 4, blk, 0, stream>>>(qkv, attnb);

  res_ln2_kernel<<<NPIX / 32, blk, 0, stream>>>(x, attnb, ln2g, ln2b, x1, n2);

  // fc1 + gelu: [N,256] x [1024,256]^T -> h [N,1024]
  gemm_regA<16, 1, 256, 1><<<dim3(512), blk, 0, stream>>>(
      n2, f1T, fc1b, nullptr, hbuf, nullptr, 256);

  // fc2 + residual + transpose: [N,1024] x [256,1024]^T -> out [B,C,H,W]
  gemm_regA<4, 8, 128, 2><<<dim3(512), blk, 0, stream>>>(
      hbuf, f2T, fc2b, x1, nullptr, out, 1024);
}